// Round 2
// 1028.323 us; speedup vs baseline: 2.1409x; 2.1409x over previous
//
#include <hip/hip_runtime.h>

typedef unsigned short u16;
typedef unsigned int   u32;
typedef unsigned long long u64;

constexpr int NROW  = 16384;   // B*T
constexpr int DIM   = 512;
constexpr int KCODE = 8192;

// MFMA argmin tiling
constexpr int BM   = 128;   // rows per block
constexpr int BN   = 128;   // codes per block
constexpr int BK   = 32;    // depth chunk
constexpr int LSTR = 36;    // LDS row stride (ushort): 72 B => 2-way-free b64 reads

// d_out offsets (in floats)
constexpr size_t Q_OFF = 0;          // quantized_st [16,1024,512]
constexpr size_t T_OFF = 8388608;    // targets [16,1024]
constexpr size_t L_OFF = 8404992;    // extra_losses scalar
constexpr size_t E_OFF = 8404993;    // new_embeddings [8192,512]
constexpr size_t C_OFF = 12599297;   // new_cs [8192]
constexpr size_t W_OFF = 12607489;   // new_w [8192,512]

// ws offsets (bytes)
constexpr size_t WS_KEYS   = 0;        // u64[NROW]
constexpr size_t WS_CSIZE  = 131072;   // float[KCODE]
constexpr size_t WS_COMMIT = 163840;   // float
constexpr size_t WS_CSSUM  = 163844;   // float
constexpr size_t WS_XNORM  = 196608;   // float[NROW]
constexpr size_t WS_ENORM  = 262144;   // float[KCODE]
constexpr size_t WS_ESUM   = 327680;   // float[KCODE*DIM]
constexpr size_t WS_NEEDED = WS_ESUM + (size_t)KCODE * DIM * 4;

// ---------------- kernel 1: row sum-of-squares, numpy pairwise order --------
__global__ void rownorm_kernel(const float* __restrict__ src, float* __restrict__ dst) {
    #pragma clang fp contract(off)
    __shared__ float s[4][DIM];
    __shared__ float rr[4][32];
    const int wave = threadIdx.x >> 6, lane = threadIdx.x & 63;
    const int row = blockIdx.x * 4 + wave;
    const float4* p = (const float4*)(src + (size_t)row * DIM);
    float4 v0 = p[lane];
    float4 v1 = p[lane + 64];
    *(float4*)&s[wave][lane * 4] = v0;
    *(float4*)&s[wave][(lane + 64) * 4] = v1;
    __syncthreads();
    if (lane < 32) {
        const int b = lane >> 3, j = lane & 7;
        const float* q = &s[wave][b * 128 + j];
        float x = q[0];
        float r = x * x;
        for (int t = 1; t < 16; ++t) {
            float y = q[8 * t];
            float py = y * y;
            r = r + py;
        }
        rr[wave][lane] = r;
    }
    __syncthreads();
    if (lane == 0) {
        const float* R = rr[wave];
        float B0 = ((R[0] + R[1]) + (R[2] + R[3])) + ((R[4] + R[5]) + (R[6] + R[7]));
        float B1 = ((R[8] + R[9]) + (R[10] + R[11])) + ((R[12] + R[13]) + (R[14] + R[15]));
        float B2 = ((R[16] + R[17]) + (R[18] + R[19])) + ((R[20] + R[21]) + (R[22] + R[23]));
        float B3 = ((R[24] + R[25]) + (R[26] + R[27])) + ((R[28] + R[29]) + (R[30] + R[31]));
        dst[row] = (B0 + B1) + (B2 + B3);
    }
}

// ---------------- kernel 2: argmin via split-bf16 MFMA ----------------------
typedef short bf16x8 __attribute__((ext_vector_type(8)));
typedef float f32x16 __attribute__((ext_vector_type(16)));

__device__ __forceinline__ bf16x8 ld_frag(const u16* p) {
    uint2 a = *(const uint2*)p;
    uint2 b = *(const uint2*)(p + 4);
    int4 t = make_int4((int)a.x, (int)a.y, (int)b.x, (int)b.y);
    return __builtin_bit_cast(bf16x8, t);
}

// fp32 -> bf16 round-to-nearest-even (non-NaN inputs), as u32 in low 16 bits
__device__ __forceinline__ u32 bf16rne(float x) {
    u32 u = __float_as_uint(x);
    return (u + 0x7fffu + ((u >> 16) & 1u)) >> 16;
}

// fp32x4 -> bf16 hi (RNE) + bf16 lo (RNE of residual); packed pairs
__device__ __forceinline__ void split4(float4 v, u32& hp0, u32& hp1, u32& lp0, u32& lp1) {
    u32 h0 = bf16rne(v.x), h1 = bf16rne(v.y), h2 = bf16rne(v.z), h3 = bf16rne(v.w);
    hp0 = h0 | (h1 << 16);
    hp1 = h2 | (h3 << 16);
    float r0 = v.x - __uint_as_float(h0 << 16);
    float r1 = v.y - __uint_as_float(h1 << 16);
    float r2 = v.z - __uint_as_float(h2 << 16);
    float r3 = v.w - __uint_as_float(h3 << 16);
    lp0 = bf16rne(r0) | (bf16rne(r1) << 16);
    lp1 = bf16rne(r2) | (bf16rne(r3) << 16);
}

__device__ __forceinline__ u64 packkey(float v, int code) {
    u32 vb = __float_as_uint(v);
    vb = (vb & 0x80000000u) ? ~vb : (vb | 0x80000000u);
    return ((u64)vb << 32) | (u32)code;
}

__launch_bounds__(256, 3)
__global__ void argmin_kernel(const float* __restrict__ feat,
                              const float* __restrict__ emb,
                              const float* __restrict__ xnorm,
                              const float* __restrict__ enorm,
                              u64* __restrict__ keys) {
    __shared__ u16 sAh[BM][LSTR], sAl[BM][LSTR], sBh[BN][LSTR], sBl[BN][LSTR];
    __shared__ float sXn[BM], sEn[BN];

    const int tid = threadIdx.x;
    // XCD-bijective swizzle: 8192 % 8 == 0; cp varies fastest inside an XCD
    const int swz = ((int)blockIdx.x & 7) * 1024 + ((int)blockIdx.x >> 3);
    const int cp = swz & 63;    // 64 code panels
    const int rp = swz >> 6;    // 128 row panels
    const int row0 = rp * BM;
    const int code0 = cp * BN;

    if (tid < BM) sXn[tid] = xnorm[row0 + tid];
    else          sEn[tid - BM] = enorm[code0 + (tid - BM)];

    // staging: thread -> (row = tid>>3 [+32*l], 4-float col = (tid&7)*4); fully coalesced
    const int srow = tid >> 3;
    const int scol = (tid & 7) * 4;
    const float* aBase = feat + (size_t)row0 * DIM;
    const float* bBase = emb + (size_t)code0 * DIM;

    float4 pa[4], pb[4];
    #pragma unroll
    for (int l = 0; l < 4; ++l) {
        pa[l] = *(const float4*)&aBase[(size_t)(srow + 32 * l) * DIM + scol];
        pb[l] = *(const float4*)&bBase[(size_t)(srow + 32 * l) * DIM + scol];
    }

    const int lane = tid & 63;
    const int wv = tid >> 6;
    const int wr = wv & 1, wc = wv >> 1;    // 2x2 waves over 64x64 sub-tiles
    const int c5 = lane & 31, hgrp = lane >> 5;

    f32x16 acc[2][2] = {};

    #pragma unroll 1
    for (int kt = 0; kt < DIM / BK; ++kt) {
        __syncthreads();
        // convert + LDS write phase
        #pragma unroll
        for (int l = 0; l < 4; ++l) {
            u32 h0, h1, q0, q1;
            split4(pa[l], h0, h1, q0, q1);
            *(uint2*)&sAh[srow + 32 * l][scol] = make_uint2(h0, h1);
            *(uint2*)&sAl[srow + 32 * l][scol] = make_uint2(q0, q1);
            split4(pb[l], h0, h1, q0, q1);
            *(uint2*)&sBh[srow + 32 * l][scol] = make_uint2(h0, h1);
            *(uint2*)&sBl[srow + 32 * l][scol] = make_uint2(q0, q1);
        }
        __syncthreads();
        // issue next-chunk global loads; land during MFMA phase
        if (kt + 1 < DIM / BK) {
            const int k0 = (kt + 1) * BK;
            #pragma unroll
            for (int l = 0; l < 4; ++l) {
                pa[l] = *(const float4*)&aBase[(size_t)(srow + 32 * l) * DIM + k0 + scol];
                pb[l] = *(const float4*)&bBase[(size_t)(srow + 32 * l) * DIM + k0 + scol];
            }
        }
        // MFMA phase: 3-pass split-bf16 (xh*eh + xh*el + xl*eh)
        #pragma unroll
        for (int s = 0; s < 2; ++s) {
            const int kk = s * 16 + hgrp * 8;
            bf16x8 ah[2], al[2], bh[2], bl[2];
            #pragma unroll
            for (int i = 0; i < 2; ++i) {
                ah[i] = ld_frag(&sAh[64 * wr + 32 * i + c5][kk]);
                al[i] = ld_frag(&sAl[64 * wr + 32 * i + c5][kk]);
                bh[i] = ld_frag(&sBh[64 * wc + 32 * i + c5][kk]);
                bl[i] = ld_frag(&sBl[64 * wc + 32 * i + c5][kk]);
            }
            #pragma unroll
            for (int i = 0; i < 2; ++i) {
                #pragma unroll
                for (int j = 0; j < 2; ++j) {
                    acc[i][j] = __builtin_amdgcn_mfma_f32_32x32x16_bf16(ah[i], bh[j], acc[i][j], 0, 0, 0);
                    acc[i][j] = __builtin_amdgcn_mfma_f32_32x32x16_bf16(ah[i], bl[j], acc[i][j], 0, 0, 0);
                    acc[i][j] = __builtin_amdgcn_mfma_f32_32x32x16_bf16(al[i], bh[j], acc[i][j], 0, 0, 0);
                }
            }
        }
    }

    // epilogue: d2 = (xn - 2*dot) + en, per-row argmin, same key protocol as before
    #pragma unroll
    for (int i = 0; i < 2; ++i) {
        #pragma unroll
        for (int r = 0; r < 16; ++r) {
            const int rowt = 64 * wr + 32 * i + (r & 3) + 8 * (r >> 2) + 4 * hgrp;
            const float xv = sXn[rowt];
            const int ct0 = 64 * wc + c5;
            float v0 = fmaf(-2.0f, acc[i][0][r], xv) + sEn[ct0];
            float v1 = fmaf(-2.0f, acc[i][1][r], xv) + sEn[ct0 + 32];
            u64 ka = packkey(v0, code0 + ct0);
            u64 kb = packkey(v1, code0 + ct0 + 32);
            u64 key = (kb < ka) ? kb : ka;
            #pragma unroll
            for (int m = 1; m < 32; m <<= 1) {
                u64 o = __shfl_xor(key, m, 64);
                if (o < key) key = o;
            }
            if (c5 == 0) atomicMin(&keys[row0 + rowt], key);
        }
    }
}

// ---------------- kernel 3: gather + commitment + scatter-add ---------------
__global__ void gather_kernel(const float* __restrict__ feat,
                              const float* __restrict__ emb,
                              const unsigned long long* __restrict__ keys,
                              float* __restrict__ qout,
                              float* __restrict__ targets,
                              float* __restrict__ esum,
                              float* __restrict__ csize,
                              float* __restrict__ commit) {
    const int row = blockIdx.x;
    const int code = (int)(keys[row] & 0x7fffffffu);
    const int d = threadIdx.x * 2;
    float2 f = *(const float2*)&feat[(size_t)row * DIM + d];
    float2 q = *(const float2*)&emb[(size_t)code * DIM + d];
    float2 qst;
    qst.x = f.x + (q.x - f.x);
    qst.y = f.y + (q.y - f.y);
    *(float2*)&qout[(size_t)row * DIM + d] = qst;
    float dx = f.x - qst.x, dy = f.y - qst.y;
    float local = dx * dx + dy * dy;
    #pragma unroll
    for (int off = 32; off; off >>= 1) local += __shfl_down(local, off, 64);
    __shared__ float wsum[4];
    int lane = threadIdx.x & 63, wv = threadIdx.x >> 6;
    if (lane == 0) wsum[wv] = local;
    __syncthreads();
    if (threadIdx.x == 0) {
        atomicAdd(commit, wsum[0] + wsum[1] + wsum[2] + wsum[3]);
        atomicAdd(&csize[code], 1.0f);
        targets[row] = (float)code;
    }
    atomicAdd(&esum[(size_t)code * DIM + d], f.x);
    atomicAdd(&esum[(size_t)code * DIM + d + 1], f.y);
}

// ---------------- kernel 4: new_cs + sum(new_cs) + loss ---------------------
__global__ void newcs_kernel(const float* __restrict__ ema_cs,
                             const float* __restrict__ csize,
                             float* __restrict__ out_cs,
                             float* __restrict__ cs_sum,
                             const float* __restrict__ commit,
                             float* __restrict__ out_loss) {
    int i = blockIdx.x * 256 + threadIdx.x;
    float v = 0.99f * ema_cs[i] + 0.01f * csize[i];
    out_cs[i] = v;
    float s = v;
    #pragma unroll
    for (int off = 32; off; off >>= 1) s += __shfl_down(s, off, 64);
    __shared__ float wsum[4];
    int lane = threadIdx.x & 63, wv = threadIdx.x >> 6;
    if (lane == 0) wsum[wv] = s;
    __syncthreads();
    if (threadIdx.x == 0)
        atomicAdd(cs_sum, wsum[0] + wsum[1] + wsum[2] + wsum[3]);
    if (blockIdx.x == 0 && threadIdx.x == 0)
        out_loss[0] = 0.25f * commit[0] / 8388608.0f;
}

// ---------------- kernel 5: new_w + new_embeddings --------------------------
__global__ void final_kernel(const float* __restrict__ ema_w,
                             const float* __restrict__ esum,
                             const float* __restrict__ new_cs,
                             const float* __restrict__ cs_sum,
                             float* __restrict__ out_w,
                             float* __restrict__ out_emb) {
    size_t i4 = ((size_t)blockIdx.x * 256 + threadIdx.x) * 4;
    int k = (int)(i4 >> 9);
    float S = cs_sum[0] + (float)KCODE * 1e-5f;
    float4 es = *(const float4*)&esum[i4];
    float4 ew = *(const float4*)&ema_w[i4];
    float w0 = 0.99f * ew.x + 0.01f * es.x;
    float w1 = 0.99f * ew.y + 0.01f * es.y;
    float w2 = 0.99f * ew.z + 0.01f * es.z;
    float w3 = 0.99f * ew.w + 0.01f * es.w;
    out_w[i4 + 0] = w0; out_w[i4 + 1] = w1; out_w[i4 + 2] = w2; out_w[i4 + 3] = w3;
    float scale = S / (new_cs[k] + 1e-5f);
    out_emb[i4 + 0] = w0 * scale; out_emb[i4 + 1] = w1 * scale;
    out_emb[i4 + 2] = w2 * scale; out_emb[i4 + 3] = w3 * scale;
}

// ---------------------------------------------------------------------------
extern "C" void kernel_launch(void* const* d_in, const int* in_sizes, int n_in,
                              void* d_out, int out_size, void* d_ws, size_t ws_size,
                              hipStream_t stream) {
    const float* feat   = (const float*)d_in[0];
    const float* emb    = (const float*)d_in[1];
    const float* ema_cs = (const float*)d_in[2];
    const float* ema_w  = (const float*)d_in[3];
    float* out = (float*)d_out;
    char* ws = (char*)d_ws;
    if (ws_size < WS_NEEDED) return;

    u64* keys     = (u64*)(ws + WS_KEYS);
    float* csize  = (float*)(ws + WS_CSIZE);
    float* commit = (float*)(ws + WS_COMMIT);
    float* cssum  = (float*)(ws + WS_CSSUM);
    float* xnorm  = (float*)(ws + WS_XNORM);
    float* enorm  = (float*)(ws + WS_ENORM);
    float* esum   = (float*)(ws + WS_ESUM);

    (void)hipMemsetAsync(ws + WS_KEYS, 0xFF, (size_t)NROW * 8, stream);
    (void)hipMemsetAsync(ws + WS_CSIZE, 0, WS_CSSUM + 4 - WS_CSIZE, stream);
    (void)hipMemsetAsync(ws + WS_ESUM, 0, (size_t)KCODE * DIM * 4, stream);

    rownorm_kernel<<<NROW / 4, 256, 0, stream>>>(feat, xnorm);
    rownorm_kernel<<<KCODE / 4, 256, 0, stream>>>(emb, enorm);
    argmin_kernel<<<(NROW / BM) * (KCODE / BN), 256, 0, stream>>>(feat, emb, xnorm, enorm, keys);
    gather_kernel<<<NROW, 256, 0, stream>>>(feat, emb, keys, out + Q_OFF, out + T_OFF,
                                            esum, csize, commit);
    newcs_kernel<<<KCODE / 256, 256, 0, stream>>>(ema_cs, csize, out + C_OFF, cssum, commit, out + L_OFF);
    final_kernel<<<KCODE * DIM / 1024, 256, 0, stream>>>(ema_w, esum, out + C_OFF, cssum,
                                                         out + W_OFF, out + E_OFF);
}